// Round 4
// baseline (2714.594 us; speedup 1.0000x reference)
//
#include <hip/hip_runtime.h>

// Problem constants
#define M_TOK 32000   // B*T tokens
#define DIM   512     // feature dim
#define KCB   1024    // codebook size
#define NQ    8       // quantizer stages
// Tiling: block = 64 tokens x full N=1024; 8 waves in 4(M) x 2(N) grid.
#define BM 64
#define THREADS 512
#define NCCH 4        // N chunks of 256 cols
#define KS 16         // K steps of 32

typedef _Float16 f16x8 __attribute__((ext_vector_type(8)));
typedef _Float16 f16x4 __attribute__((ext_vector_type(4)));
typedef float f32x4 __attribute__((ext_vector_type(4)));

__device__ __forceinline__ float wave_reduce_sum(float v) {
#pragma unroll
  for (int off = 32; off > 0; off >>= 1) v += __shfl_xor(v, off, 64);
  return v;
}

// Monotone float->uint mapping: a<b (float) <=> fenc(a)<fenc(b) (uint)
__device__ __forceinline__ unsigned int fenc(float f) {
  unsigned int u = __float_as_uint(f);
  return (u & 0x80000000u) ? ~u : (u | 0x80000000u);
}

// ---------------- init: e2 (all stages), r2 (from x), lossCell ----------------
__global__ __launch_bounds__(256) void rvq_init_kernel(
    const float* __restrict__ x, const float* __restrict__ cb,
    float* __restrict__ e2, float* __restrict__ r2, float* __restrict__ lossCell) {
  if (blockIdx.x == 0 && threadIdx.x == 0) *lossCell = 0.f;
  int row = blockIdx.x * 4 + (threadIdx.x >> 6);
  int lane = threadIdx.x & 63;
  const float* src;
  float* dst;
  if (row < NQ * KCB) {
    src = cb + (size_t)row * DIM;
    dst = e2 + row;
  } else {
    int t = row - NQ * KCB;
    if (t >= M_TOK) return;
    src = x + (size_t)t * DIM;
    dst = r2 + t;
  }
  const float4* s4 = (const float4*)src;
  float s = 0.f;
  float4 v = s4[lane];
  s += v.x * v.x + v.y * v.y + v.z * v.z + v.w * v.w;
  v = s4[lane + 64];
  s += v.x * v.x + v.y * v.y + v.z * v.z + v.w * v.w;
  s = wave_reduce_sum(s);
  if (lane == 0) *dst = s;
}

// ------- pre-split codebooks to hi/lo fp16 in MFMA-FRAGMENT order -------
// Fragment (s, F, c): cols F*16..+15, k = c*32 + (lane>>4)*8 + j; flat thread
// id == fragment-lane slot, so writes are perfectly coalesced 16B/lane.
__global__ __launch_bounds__(256) void rvq_split_cb_kernel(
    const float* __restrict__ cb, _Float16* __restrict__ cbhF,
    _Float16* __restrict__ cblF) {
  int gid = blockIdx.x * 256 + threadIdx.x;  // (((s*64+F)*16+c)*64+l)
  int l = gid & 63;
  int c = (gid >> 6) & 15;
  int F = (gid >> 10) & 63;
  int s = gid >> 16;
  if (s >= NQ) return;
  const float* src = cb + (size_t)(s * KCB + F * 16 + (l & 15)) * DIM
                        + c * 32 + (l >> 4) * 8;
  f16x8 h, lo;
#pragma unroll
  for (int j = 0; j < 8; ++j) {
    float v = src[j];
    _Float16 hh = (_Float16)v;
    h[j] = hh;
    lo[j] = (_Float16)(v - (float)hh);  // exact by Sterbenz, then rn
  }
  *(f16x8*)(cbhF + (size_t)gid * 8) = h;
  *(f16x8*)(cblF + (size_t)gid * 8) = lo;
}

// ---------------- fused stage: full-N argmin + in-block update ----------------
// A (64 tokens, full K) split hi/lo in LDS once; B fragments streamed from L2
// into registers; barrier-free K loop; block-local argmin is globally final,
// so the straight-through update + loss fold into the epilogue.
__global__ __launch_bounds__(THREADS, 2) void rvq_stage_kernel(
    const float* __restrict__ rin,     // [32000][512] fp32 residual
    const _Float16* __restrict__ cbhF, // stage fragment-ordered hi
    const _Float16* __restrict__ cblF, // stage fragment-ordered lo
    const float* __restrict__ cb32,    // stage fp32 codebook (gather)
    const float* __restrict__ e2,      // [1024] stage norms
    const float* __restrict__ r2,      // [32000] token norms (this stage)
    float* __restrict__ rout, float* __restrict__ r2out,
    float* __restrict__ idx_out, float* __restrict__ lossCell) {
  __shared__ __align__(16) _Float16 sA[2][BM * DIM];  // hi, lo: 128 KB
  __shared__ unsigned long long sWin[BM][2];          // per-wc winners

  const int tid = threadIdx.x;
  const int lane = tid & 63;
  const int w = tid >> 6;   // 0..7
  const int wr = w >> 1;    // M quarter (16 rows)
  const int wc = w & 1;     // N half of 256-chunk (128 cols)
  const int l15 = lane & 15, l4 = lane >> 4;
  const int m0 = blockIdx.x * BM;

  // ---- preload A: fp32 -> split fp16 hi/lo into XOR-swizzled LDS ----
#pragma unroll
  for (int i = 0; i < 16; ++i) {
    int idx = tid + i * THREADS;  // float4 slot in [64][128]
    int row = idx >> 7, k4 = idx & 127;
    float4 v = *(const float4*)(rin + (size_t)(m0 + row) * DIM + k4 * 4);
    float vv[4] = {v.x, v.y, v.z, v.w};
    f16x4 h, l;
#pragma unroll
    for (int j = 0; j < 4; ++j) {
      _Float16 hh = (_Float16)vv[j];
      h[j] = hh;
      l[j] = (_Float16)(vv[j] - (float)hh);
    }
    int off = (row * 1024 + k4 * 8) ^ ((row & 7) << 4);
    *(f16x4*)((char*)sA[0] + off) = h;
    *(f16x4*)((char*)sA[1] + off) = l;
  }
  __syncthreads();

  // token norms for this wave's 16 rows (broadcast float4 per l4 group)
  float4 r2q = *(const float4*)(r2 + m0 + wr * 16 + l4 * 4);
  float rv[4] = {r2q.x, r2q.y, r2q.z, r2q.w};

  float minv[4];
  int mini[4];
#pragma unroll
  for (int i = 0; i < 4; ++i) { minv[i] = 3.4e38f; mini[i] = 0; }

  const int arow = wr * 16 + l15;
  const int abase = arow * 1024;
  const int aswz = (arow & 7) << 4;

  for (int nc = 0; nc < NCCH; ++nc) {
    f32x4 acc[8];
#pragma unroll
    for (int nf = 0; nf < 8; ++nf) acc[nf] = (f32x4){0.f, 0.f, 0.f, 0.f};
    const int Fbase = nc * 16 + wc * 8;

    for (int ks = 0; ks < KS; ++ks) {
      __builtin_amdgcn_s_barrier();  // scheduling sync only: keeps the 4
                                     // same-wc waves L1-coherent on B
      // B fragments: coalesced 16B/lane from L2 (fragment-ordered)
      f16x8 bh[8], bl[8];
#pragma unroll
      for (int nf = 0; nf < 8; ++nf) {
        size_t boff = ((size_t)((Fbase + nf) * 16 + ks) * 64 + lane) * 8;
        bh[nf] = *(const f16x8*)(cbhF + boff);
        bl[nf] = *(const f16x8*)(cblF + boff);
      }
      // A fragments from LDS
      int aoff = (abase + ks * 64 + l4 * 16) ^ aswz;
      f16x8 ah = *(const f16x8*)((const char*)sA[0] + aoff);
      f16x8 al = *(const f16x8*)((const char*)sA[1] + aoff);
#pragma unroll
      for (int nf = 0; nf < 8; ++nf) {
        acc[nf] = __builtin_amdgcn_mfma_f32_16x16x32_f16(ah, bh[nf], acc[nf], 0, 0, 0);
        acc[nf] = __builtin_amdgcn_mfma_f32_16x16x32_f16(ah, bl[nf], acc[nf], 0, 0, 0);
        acc[nf] = __builtin_amdgcn_mfma_f32_16x16x32_f16(al, bh[nf], acc[nf], 0, 0, 0);
      }
    }
    // fold chunk into running argmin: dist = (r2 - 2*dot) + e2
#pragma unroll
    for (int nf = 0; nf < 8; ++nf) {
      int col = nc * 256 + wc * 128 + nf * 16 + l15;
      float e2v = e2[col];
#pragma unroll
      for (int rr = 0; rr < 4; ++rr) {
        float d = (rv[rr] - 2.f * acc[nf][rr]) + e2v;
        if (d < minv[rr]) { minv[rr] = d; mini[rr] = col; }
      }
    }
  }

  // 16-lane reduce (cols within wave), winners to LDS
#pragma unroll
  for (int rr = 0; rr < 4; ++rr) {
    float v = minv[rr];
    int ix = mini[rr];
#pragma unroll
    for (int off = 8; off; off >>= 1) {
      float ov = __shfl_xor(v, off, 16);
      int oi = __shfl_xor(ix, off, 16);
      if (ov < v || (ov == v && oi < ix)) { v = ov; ix = oi; }
    }
    if (l15 == 0)
      sWin[wr * 16 + l4 * 4 + rr][wc] =
          ((unsigned long long)fenc(v) << 32) | (unsigned)ix;
  }
  __syncthreads();

  // ---- epilogue: straight-through update, loss, next r2 (8 rows/wave) ----
  float lpart = 0.f;
#pragma unroll
  for (int i = 0; i < 8; ++i) {
    const int r = w * 8 + i;
    const int tok = m0 + r;
    unsigned long long k0 = sWin[r][0], k1 = sWin[r][1];
    unsigned idx = (unsigned)((k0 < k1 ? k0 : k1) & 0xffffffffu);
    const float4* rrow = (const float4*)(rin + (size_t)tok * DIM);
    const float4* crow = (const float4*)(cb32 + (size_t)idx * DIM);
    float4* orow = (float4*)(rout + (size_t)tok * DIM);
    float ssq_t = 0.f, ssq_r = 0.f;
#pragma unroll
    for (int c4 = 0; c4 < 2; ++c4) {
      int c = lane + c4 * 64;
      float4 a = rrow[c], q = crow[c];
      // t = q - r; qst = r + t; r_new = r - qst; loss += t^2  (ref rounding)
      float4 t = make_float4(q.x - a.x, q.y - a.y, q.z - a.z, q.w - a.w);
      float4 qst = make_float4(a.x + t.x, a.y + t.y, a.z + t.z, a.w + t.w);
      float4 rn = make_float4(a.x - qst.x, a.y - qst.y, a.z - qst.z, a.w - qst.w);
      orow[c] = rn;
      ssq_t += t.x * t.x + t.y * t.y + t.z * t.z + t.w * t.w;
      ssq_r += rn.x * rn.x + rn.y * rn.y + rn.z * rn.z + rn.w * rn.w;
    }
    float tot_t = wave_reduce_sum(ssq_t);
    float tot_r = wave_reduce_sum(ssq_r);
    if (lane == 0) {
      idx_out[tok] = (float)idx;
      r2out[tok] = tot_r;
      lpart += tot_t;
    }
  }
  if (lane == 0) atomicAdd(lossCell, lpart);
}

// ---------------- finalize: out = x - r8, loss scale ----------------
__global__ __launch_bounds__(256) void rvq_finalize_kernel(
    const float* __restrict__ x, float* __restrict__ out,
    const float* __restrict__ lossCell, float* __restrict__ loss_out) {
  size_t i = (size_t)blockIdx.x * 256 + threadIdx.x;
  const size_t n4 = (size_t)M_TOK * DIM / 4;
  if (i < n4) {
    const float4* x4 = (const float4*)x;
    float4* o4 = (float4*)out;
    float4 a = x4[i], r = o4[i];
    o4[i] = make_float4(a.x - r.x, a.y - r.y, a.z - r.z, a.w - r.w);
  }
  if (blockIdx.x == 0 && threadIdx.x == 0) {
    // mean over stages of 1.25*mean_elem(t^2): 1.25 / (8 * 16384000)
    *loss_out = *lossCell * (1.25f / 131072000.f);
  }
}

extern "C" void kernel_launch(void* const* d_in, const int* in_sizes, int n_in,
                              void* d_out, int out_size, void* d_ws, size_t ws_size,
                              hipStream_t stream) {
  const float* x = (const float*)d_in[0];        // [16,2000,512]
  const float* cb = (const float*)d_in[1];       // [8,1024,512]
  float* out = (float*)d_out;                    // quantized region = residual buffer
  float* idx_out = out + (size_t)M_TOK * DIM;    // [8][32000] indices as float
  float* loss_out = idx_out + (size_t)NQ * M_TOK;

  // ws layout: cbhF (8MB) | cblF (8MB) | e2 | r2 | lossCell
  char* wsp = (char*)d_ws;
  _Float16* cbhF = (_Float16*)wsp;
  _Float16* cblF = cbhF + (size_t)NQ * KCB * DIM;
  float* e2 = (float*)(cblF + (size_t)NQ * KCB * DIM);
  float* r2 = e2 + NQ * KCB;
  float* lossCell = r2 + M_TOK;

  {
    int rows = NQ * KCB + M_TOK;  // 40192
    rvq_init_kernel<<<(rows + 3) / 4, 256, 0, stream>>>(x, cb, e2, r2, lossCell);
    rvq_split_cb_kernel<<<NQ * 64 * 16 * 64 / 256, 256, 0, stream>>>(cb, cbhF, cblF);
  }
  float* resbuf = out;
  for (int s = 0; s < NQ; ++s) {
    const float* rin = (s == 0) ? x : resbuf;
    rvq_stage_kernel<<<M_TOK / BM, THREADS, 0, stream>>>(
        rin, cbhF + (size_t)s * KCB * DIM, cblF + (size_t)s * KCB * DIM,
        cb + (size_t)s * KCB * DIM, e2 + s * KCB, r2,
        resbuf, r2, idx_out + (size_t)s * M_TOK, lossCell);
  }
  rvq_finalize_kernel<<<(M_TOK * DIM / 4 + 255) / 256, 256, 0, stream>>>(
      x, out, lossCell, loss_out);
}

// Round 5
// 1284.145 us; speedup vs baseline: 2.1139x; 2.1139x over previous
//
#include <hip/hip_runtime.h>

// Problem constants
#define M_TOK 32000   // B*T tokens
#define DIM   512     // feature dim
#define KCB   1024    // codebook size
#define NQ    8       // quantizer stages
// Tiling: block = 64 tokens x 256 cols, 4 waves (each 64x64), K-steps of 32.
#define BM 64
#define BN 256
#define KS 16

typedef _Float16 f16x8 __attribute__((ext_vector_type(8)));
typedef _Float16 f16x4 __attribute__((ext_vector_type(4)));
typedef float f32x4 __attribute__((ext_vector_type(4)));

#define FENCE() __builtin_amdgcn_sched_barrier(0)
#define WAIT_VM(N) asm volatile("s_waitcnt vmcnt(" #N ")" ::: "memory")
#define WAIT_LGKM0() asm volatile("s_waitcnt lgkmcnt(0)" ::: "memory")

__device__ __forceinline__ void gload_lds16(const void* g, void* l) {
  __builtin_amdgcn_global_load_lds(
      (const __attribute__((address_space(1))) unsigned int*)g,
      (__attribute__((address_space(3))) unsigned int*)l, 16, 0, 0);
}

__device__ __forceinline__ float wave_reduce_sum(float v) {
#pragma unroll
  for (int off = 32; off > 0; off >>= 1) v += __shfl_xor(v, off, 64);
  return v;
}

// Monotone float->uint mapping: a<b (float) <=> fenc(a)<fenc(b) (uint)
__device__ __forceinline__ unsigned int fenc(float f) {
  unsigned int u = __float_as_uint(f);
  return (u & 0x80000000u) ? ~u : (u | 0x80000000u);
}

// ---------------- init: e2, r2, keys, lossCell ----------------
__global__ __launch_bounds__(256) void rvq_init_kernel(
    const float* __restrict__ x, const float* __restrict__ cb,
    float* __restrict__ e2, float* __restrict__ r2,
    unsigned long long* __restrict__ keys, float* __restrict__ lossCell) {
  if (blockIdx.x == 0 && threadIdx.x == 0) *lossCell = 0.f;
  for (int i = blockIdx.x * 256 + threadIdx.x; i < M_TOK; i += gridDim.x * 256)
    keys[i] = ~0ull;
  int row = blockIdx.x * 4 + (threadIdx.x >> 6);
  int lane = threadIdx.x & 63;
  const float* src;
  float* dst;
  if (row < NQ * KCB) {
    src = cb + (size_t)row * DIM;
    dst = e2 + row;
  } else {
    int t = row - NQ * KCB;
    if (t >= M_TOK) return;
    src = x + (size_t)t * DIM;
    dst = r2 + t;
  }
  const float4* s4 = (const float4*)src;
  float s = 0.f;
  float4 v = s4[lane];
  s += v.x * v.x + v.y * v.y + v.z * v.z + v.w * v.w;
  v = s4[lane + 64];
  s += v.x * v.x + v.y * v.y + v.z * v.z + v.w * v.w;
  s = wave_reduce_sum(s);
  if (lane == 0) *dst = s;
}

// ---- pre-split codebooks into staging-ordered hi/lo fp16 chunks ----
// Layout: [s8][ks16][nc4][w4][c8][lane64][16B], c = nf*2 + h. A linear
// global_load_lds copy of chunk c lands exactly at the fragment the MFMA
// reads: lane l holds B[col = nf*16 + (l&15)][k = ks*32 + (l>>4)*8 + j].
__global__ __launch_bounds__(256) void rvq_split_cb_kernel(
    const float* __restrict__ cb, _Float16* __restrict__ cbF) {
  int gid = blockIdx.x * 256 + threadIdx.x;  // (s,ks,nc,w,nf,lane)
  if (gid >= NQ * 16 * 4 * 4 * 4 * 64) return;
  int lane = gid & 63;
  int nf = (gid >> 6) & 3;
  int w  = (gid >> 8) & 3;
  int nc = (gid >> 10) & 3;
  int ks = (gid >> 12) & 15;
  int s  = gid >> 16;
  int col = nc * 256 + w * 64 + nf * 16 + (lane & 15);
  int kbase = ks * 32 + (lane >> 4) * 8;
  const float* src = cb + ((size_t)s * KCB + col) * DIM + kbase;
  f16x8 h, l;
#pragma unroll
  for (int j = 0; j < 8; ++j) {
    float v = src[j];
    _Float16 hh = (_Float16)v;
    h[j] = hh;
    l[j] = (_Float16)(v - (float)hh);  // exact by Sterbenz, then rn
  }
  size_t base = ((((size_t)((s * 16 + ks) * 4 + nc) * 4 + w) * 8 + nf * 2) * 64
                 + lane) * 8;
  *(f16x8*)(cbF + base) = h;           // chunk c = nf*2   (hi)
  *(f16x8*)(cbF + base + 512) = l;     // chunk c = nf*2+1 (lo)
}

// -------- fused distance GEMM + argmin, counted-vmcnt pipeline --------
__global__ __launch_bounds__(256, 2) void rvq_argmin_kernel(
    const float* __restrict__ rin,     // [32000][512] fp32 residual
    const _Float16* __restrict__ cbF,  // this stage's staging-ordered hi/lo
    const float* __restrict__ e2,      // [1024]
    const float* __restrict__ r2,      // [32000]
    unsigned long long* __restrict__ keys) {
  // bufB: per-wave slices -> no cross-wave B dependency (no barrier needed
  // for B; its readiness is guaranteed by each wave's own counted vmcnt).
  __shared__ __align__(16) _Float16 bufB[2][4][8][512];  // 64 KB
  __shared__ __align__(16) _Float16 bufA[2][4][2][512];  // 16 KB

  const int tid = threadIdx.x;
  const int lane = tid & 63, w = tid >> 6;
  const int l15 = lane & 15, l4 = lane >> 4;
  // XCD-aware decomposition: grid 2000 = 8 xcd-slots x 250
  const int x = blockIdx.x & 7, i = blockIdx.x >> 3;
  const int nc = x >> 1;                 // col chunk 0..3
  const int m = (x & 1) * 250 + i;       // 0..499
  const int m0 = m * BM;
  const int c0 = nc * BN;

  const _Float16* gB = cbF + (((size_t)nc * 4 + w) * 8) * 512 + (size_t)lane * 8;
  const int p0 = tid, p1 = tid + 256;    // this thread's two float4 A-slots

  f32x4 acc[4][4];
#pragma unroll
  for (int a = 0; a < 4; ++a)
#pragma unroll
    for (int b = 0; b < 4; ++b) acc[a][b] = (f32x4){0.f, 0.f, 0.f, 0.f};

  float4 a0, a1;
  // helper lambdas ------------------------------------------------------
  auto ldA = [&](int ks, int p) {
    return *(const float4*)(rin + (size_t)(m0 + (p >> 3)) * DIM + ks * 32 + (p & 7) * 4);
  };
  auto cvtWriteA = [&](int buf, const float4& v, int p) {
    int r = p >> 3, kg = p & 7;
    int mf = r >> 4, lp = (kg >> 1) * 16 + (r & 15), fo = (kg & 1) * 4;
    float vv[4] = {v.x, v.y, v.z, v.w};
    f16x4 h, l;
#pragma unroll
    for (int j = 0; j < 4; ++j) {
      _Float16 hh = (_Float16)vv[j];
      h[j] = hh;
      l[j] = (_Float16)(vv[j] - (float)hh);
    }
    *(f16x4*)&bufA[buf][mf][0][lp * 8 + fo] = h;
    *(f16x4*)&bufA[buf][mf][1][lp * 8 + fo] = l;
  };
  // prologue: A(0) regs first, then B(0) lds-loads; wait only A.
  a0 = ldA(0, p0);
  a1 = ldA(0, p1);
  FENCE();
#pragma unroll
  for (int c = 0; c < 8; ++c)
    gload_lds16(gB + c * 512, &bufB[0][w][c][0]);
  WAIT_VM(8);
  FENCE();
  cvtWriteA(0, a0, p0);
  cvtWriteA(0, a1, p1);

  for (int ks = 0; ks < KS; ++ks) {
    const int cur = ks & 1;
    if (ks < KS - 1) {
      a0 = ldA(ks + 1, p0);
      a1 = ldA(ks + 1, p1);
      FENCE();
      const _Float16* gBs = gB + (size_t)(ks + 1) * 65536;
#pragma unroll
      for (int c = 0; c < 8; ++c)
        gload_lds16(gBs + c * 512, &bufB[cur ^ 1][w][c][0]);
      WAIT_VM(10);   // B(ks) landed; B(ks+1)+A(ks+1) = 10 still in flight
    } else {
      WAIT_VM(0);
    }
    FENCE();
    WAIT_LGKM0();    // our A ds_writes committed before the barrier
    FENCE();
    __builtin_amdgcn_s_barrier();
    FENCE();
    // ---- compute on buffers [cur] ----
    f16x8 ah[4], al[4];
#pragma unroll
    for (int mf = 0; mf < 4; ++mf) {
      ah[mf] = *(const f16x8*)&bufA[cur][mf][0][lane * 8];
      al[mf] = *(const f16x8*)&bufA[cur][mf][1][lane * 8];
    }
    __builtin_amdgcn_s_setprio(1);
#pragma unroll
    for (int nf = 0; nf < 4; ++nf) {
      f16x8 bh = *(const f16x8*)&bufB[cur][w][nf * 2][lane * 8];
      f16x8 bl = *(const f16x8*)&bufB[cur][w][nf * 2 + 1][lane * 8];
#pragma unroll
      for (int mf = 0; mf < 4; ++mf) {
        acc[mf][nf] = __builtin_amdgcn_mfma_f32_16x16x32_f16(ah[mf], bh, acc[mf][nf], 0, 0, 0);
        acc[mf][nf] = __builtin_amdgcn_mfma_f32_16x16x32_f16(ah[mf], bl, acc[mf][nf], 0, 0, 0);
        acc[mf][nf] = __builtin_amdgcn_mfma_f32_16x16x32_f16(al[mf], bh, acc[mf][nf], 0, 0, 0);
      }
    }
    __builtin_amdgcn_s_setprio(0);
    if (ks < KS - 1) {  // convert+publish A(ks+1); compiler waits vmcnt(8)
      cvtWriteA(cur ^ 1, a0, p0);
      cvtWriteA(cur ^ 1, a1, p1);
    }
  }

  // ---- fold: dist = (r2 - 2*dot) + e2; min over this block's 256 cols ----
  float rv[4][4];
#pragma unroll
  for (int mf = 0; mf < 4; ++mf) {
    float4 q = *(const float4*)(r2 + m0 + mf * 16 + l4 * 4);
    rv[mf][0] = q.x; rv[mf][1] = q.y; rv[mf][2] = q.z; rv[mf][3] = q.w;
  }
  float minv[16];
  int mini[16];
#pragma unroll
  for (int i2 = 0; i2 < 16; ++i2) { minv[i2] = 3.4e38f; mini[i2] = 0; }
#pragma unroll
  for (int nf = 0; nf < 4; ++nf) {
    int col = c0 + w * 64 + nf * 16 + l15;
    float e2v = e2[col];
#pragma unroll
    for (int mf = 0; mf < 4; ++mf) {
#pragma unroll
      for (int rr = 0; rr < 4; ++rr) {
        float d = (rv[mf][rr] - 2.f * acc[mf][nf][rr]) + e2v;
        int ii = mf * 4 + rr;
        if (d < minv[ii]) { minv[ii] = d; mini[ii] = col; }
      }
    }
  }
#pragma unroll
  for (int mf = 0; mf < 4; ++mf) {
#pragma unroll
    for (int rr = 0; rr < 4; ++rr) {
      int ii = mf * 4 + rr;
      float v = minv[ii];
      int ix = mini[ii];
#pragma unroll
      for (int off = 8; off; off >>= 1) {
        float ov = __shfl_xor(v, off, 16);
        int oi = __shfl_xor(ix, off, 16);
        if (ov < v || (ov == v && oi < ix)) { v = ov; ix = oi; }
      }
      if (l15 == 0) {
        int tok = m0 + mf * 16 + l4 * 4 + rr;
        unsigned long long key = ((unsigned long long)fenc(v) << 32) | (unsigned)ix;
        atomicMin(&keys[tok], key);
      }
    }
  }
}

// ---------------- per-token update (exact reference rounding) ----------------
__global__ __launch_bounds__(256) void rvq_update_kernel(
    const float* __restrict__ rin, const float* __restrict__ cb,
    unsigned long long* __restrict__ keys,
    float* __restrict__ rout, float* __restrict__ r2out,
    float* __restrict__ idx_out, float* __restrict__ lossCell) {
  const int wave = threadIdx.x >> 6, lane = threadIdx.x & 63;
  __shared__ float lred[4];
  float lpart = 0.f;
  for (int r = wave; r < 64; r += 4) {
    const int tok = blockIdx.x * 64 + r;
    const unsigned idx = (unsigned)(keys[tok] & 0xffffffffu);
    const float4* rrow = (const float4*)(rin + (size_t)tok * DIM);
    const float4* crow = (const float4*)(cb + (size_t)idx * DIM);
    float4* orow = (float4*)(rout + (size_t)tok * DIM);
    float ssq_t = 0.f, ssq_r = 0.f;
#pragma unroll
    for (int c4 = 0; c4 < 2; ++c4) {
      int c = lane + c4 * 64;
      float4 a = rrow[c], q = crow[c];
      // t = q - r; qst = r + t; r_new = r - qst; loss += t^2
      float4 t = make_float4(q.x - a.x, q.y - a.y, q.z - a.z, q.w - a.w);
      float4 qst = make_float4(a.x + t.x, a.y + t.y, a.z + t.z, a.w + t.w);
      float4 rn = make_float4(a.x - qst.x, a.y - qst.y, a.z - qst.z, a.w - qst.w);
      orow[c] = rn;
      ssq_t += t.x * t.x + t.y * t.y + t.z * t.z + t.w * t.w;
      ssq_r += rn.x * rn.x + rn.y * rn.y + rn.z * rn.z + rn.w * rn.w;
    }
    float tot_t = wave_reduce_sum(ssq_t);
    float tot_r = wave_reduce_sum(ssq_r);
    if (lane == 0) {
      idx_out[tok] = (float)idx;
      keys[tok] = ~0ull;  // re-arm for next stage
      r2out[tok] = tot_r;
      lpart += tot_t;
    }
  }
  if (lane == 0) lred[wave] = lpart;
  __syncthreads();
  if (threadIdx.x == 0)
    atomicAdd(lossCell, lred[0] + lred[1] + lred[2] + lred[3]);
}

// ---------------- finalize: out = x - r8, loss scale ----------------
__global__ __launch_bounds__(256) void rvq_finalize_kernel(
    const float* __restrict__ x, float* __restrict__ out,
    const float* __restrict__ lossCell, float* __restrict__ loss_out) {
  size_t i = (size_t)blockIdx.x * 256 + threadIdx.x;
  const size_t n4 = (size_t)M_TOK * DIM / 4;
  if (i < n4) {
    const float4* x4 = (const float4*)x;
    float4* o4 = (float4*)out;
    float4 a = x4[i], r = o4[i];
    o4[i] = make_float4(a.x - r.x, a.y - r.y, a.z - r.z, a.w - r.w);
  }
  if (blockIdx.x == 0 && threadIdx.x == 0) {
    // mean over stages of 1.25*mean_elem(t^2): 1.25 / (8 * 16384000)
    *loss_out = *lossCell * (1.25f / 131072000.f);
  }
}

extern "C" void kernel_launch(void* const* d_in, const int* in_sizes, int n_in,
                              void* d_out, int out_size, void* d_ws, size_t ws_size,
                              hipStream_t stream) {
  const float* x = (const float*)d_in[0];        // [16,2000,512]
  const float* cb = (const float*)d_in[1];       // [8,1024,512]
  float* out = (float*)d_out;                    // quantized region = residual buffer
  float* idx_out = out + (size_t)M_TOK * DIM;    // [8][32000] indices as float
  float* loss_out = idx_out + (size_t)NQ * M_TOK;

  // ws: keys (256 KB) | e2 | r2 | lossCell | cbF (16 MB, staging-ordered)
  char* wsp = (char*)d_ws;
  unsigned long long* keys = (unsigned long long*)wsp;          // 256000 B
  float* e2 = (float*)(wsp + 256000);                           // 32768 B
  float* r2 = (float*)(wsp + 288768);                           // 128000 B
  float* lossCell = (float*)(wsp + 416768);                     // 16 B
  _Float16* cbF = (_Float16*)(wsp + 416800 + 224);              // 16B aligned

  {
    int rows = NQ * KCB + M_TOK;  // 40192
    rvq_init_kernel<<<(rows + 3) / 4, 256, 0, stream>>>(x, cb, e2, r2, keys, lossCell);
    rvq_split_cb_kernel<<<NQ * 16 * 4 * 4 * 4 * 64 / 256, 256, 0, stream>>>(cb, cbF);
  }
  float* resbuf = out;
  const size_t stageF = (size_t)16 * 4 * 4 * 8 * 512;  // f16 per stage (2 MB)
  for (int s = 0; s < NQ; ++s) {
    const float* rin = (s == 0) ? x : resbuf;
    rvq_argmin_kernel<<<(M_TOK / BM) * 4, 256, 0, stream>>>(
        rin, cbF + (size_t)s * stageF, e2 + s * KCB, r2, keys);
    rvq_update_kernel<<<M_TOK / 64, 256, 0, stream>>>(
        rin, cb + (size_t)s * KCB * DIM, keys, resbuf, r2,
        idx_out + (size_t)s * M_TOK, lossCell);
  }
  rvq_finalize_kernel<<<(M_TOK * DIM / 4 + 255) / 256, 256, 0, stream>>>(
      x, out, lossCell, loss_out);
}